// Round 4
// baseline (135.192 us; speedup 1.0000x reference)
//
#include <hip/hip_runtime.h>
#include <math.h>

#define BATCH   4096
#define N_NODES 20000
#define H       4
#define BLOCK   512
#define NW      (BLOCK / 64)

__device__ __forceinline__ float waveSum(float v) {
#pragma unroll
    for (int off = 32; off > 0; off >>= 1) v += __shfl_xor(v, off);
    return v;
}

// bf16 helpers (round-to-nearest), raw bit ops
__device__ __forceinline__ ushort f2bf(float x) {
    unsigned u = __float_as_uint(x);
    u = (u + 0x7FFFu + ((u >> 16) & 1u)) >> 16;
    return (ushort)u;
}
__device__ __forceinline__ float bf2f(ushort h) {
    return __uint_as_float(((unsigned)h) << 16);
}

__global__ __launch_bounds__(BLOCK, 8) void tax_main(
    const float* __restrict__ y_pred,
    const float* __restrict__ y_true,
    const int*   __restrict__ parents,
    const float* __restrict__ alpha,
    float*       __restrict__ partial)
{
    constexpr int LSTART[H] = {0, 100, 1100, 6100};
    constexpr int LSIZE[H]  = {100, 1000, 5000, 13900};

    __shared__ __align__(8) ushort row_bf[N_NODES];   // 40,000 B
    __shared__ float sc[128];
    __shared__ float fin[6];
    __shared__ float m_s[H], invZ_s[H], dot_s[H], yts_s[H];

    const int tid = threadIdx.x;
    const int b   = blockIdx.x;
    const int wid = tid >> 6;
    const int lid = tid & 63;

    const float4* yp4 = reinterpret_cast<const float4*>(y_pred + (size_t)b * N_NODES);
    const float4* yt4 = reinterpret_cast<const float4*>(y_true + (size_t)b * N_NODES);

    // ---- phase 1: single joint stream of y_pred + y_true ----
    // per-layer online state: m (max), z (sum exp(y-m)), dot_e (sum yt*exp(y-m)), yts (sum yt)
    float mL[H], zL[H], dotL[H], ytsL[H];
#pragma unroll
    for (int l = 0; l < H; ++l) { mL[l] = -1e30f; zL[l] = 0.f; dotL[l] = 0.f; ytsL[l] = 0.f; }

#pragma unroll
    for (int l = 0; l < H; ++l) {
        const int sq = LSTART[l] / 4, nq = LSIZE[l] / 4;
        float m = mL[l], z = zL[l], dt = dotL[l], ys = ytsL[l];
        for (int i = tid; i < nq; i += BLOCK) {
            float4 v = yp4[sq + i];
            ushort4 h;
            h.x = f2bf(v.x); h.y = f2bf(v.y); h.z = f2bf(v.z); h.w = f2bf(v.w);
            *reinterpret_cast<ushort4*>(&row_bf[4 * (sq + i)]) = h;
            float qm = fmaxf(fmaxf(v.x, v.y), fmaxf(v.z, v.w));
            float mn = fmaxf(m, qm);
            float a  = __expf(m - mn);
            float e0 = __expf(v.x - mn), e1 = __expf(v.y - mn);
            float e2 = __expf(v.z - mn), e3 = __expf(v.w - mn);
            z = z * a + (e0 + e1) + (e2 + e3);
            if (l > 0) {   // layer 0 contributes no cce terms; skip its y_true read
                float4 t = yt4[sq + i];
                dt = dt * a + t.x * e0 + t.y * e1 + t.z * e2 + t.w * e3;
                ys += (t.x + t.y) + (t.z + t.w);
            }
            m = mn;
        }
        mL[l] = m; zL[l] = z; dotL[l] = dt; ytsL[l] = ys;
    }

    // wave-level merge of (m, z, dot_e, yts) for all layers (register-only)
#pragma unroll
    for (int l = 0; l < H; ++l) {
        float m = mL[l], z = zL[l], dt = dotL[l], ys = ytsL[l];
#pragma unroll
        for (int off = 32; off > 0; off >>= 1) {
            float m2 = __shfl_xor(m, off), z2 = __shfl_xor(z, off);
            float d2 = __shfl_xor(dt, off), y2 = __shfl_xor(ys, off);
            float mn = fmaxf(m, m2);
            float aa = __expf(m - mn), bb = __expf(m2 - mn);
            z = z * aa + z2 * bb;
            dt = dt * aa + d2 * bb;
            m = mn; ys += y2;
        }
        if (lid == 0) {
            sc[wid * 16 + l * 4 + 0] = m;
            sc[wid * 16 + l * 4 + 1] = z;
            sc[wid * 16 + l * 4 + 2] = dt;
            sc[wid * 16 + l * 4 + 3] = ys;
        }
    }
    __syncthreads();   // also covers row_bf staging

    if (tid < H) {
        float m = -1e30f, z = 0.f, dt = 0.f, ys = 0.f;
        for (int w = 0; w < NW; ++w) {
            float m2 = sc[w * 16 + tid * 4 + 0], z2 = sc[w * 16 + tid * 4 + 1];
            float d2 = sc[w * 16 + tid * 4 + 2], y2 = sc[w * 16 + tid * 4 + 3];
            float mn = fmaxf(m, m2);
            float aa = __expf(m - mn), bb = __expf(m2 - mn);
            z = z * aa + z2 * bb;
            dt = dt * aa + d2 * bb;
            m = mn; ys += y2;
        }
        m_s[tid]    = m;
        invZ_s[tid] = 1.f / z;
        dot_s[tid]  = dt;     // dot_e relative to final m; true dot = dot_e * invZ
        yts_s[tid]  = ys;
    }
    __syncthreads();

    // ---- phase 2: LDS-only — S = sum exp(p), D = sum relu(p - pp) per layer ----
#pragma unroll
    for (int l = 1; l < H; ++l) {
        const int s = LSTART[l], nq = LSIZE[l] / 4;
        const float m  = m_s[l],     invZ  = invZ_s[l];
        const float mp = m_s[l - 1], invZp = invZ_s[l - 1];
        const int4* pa4 = reinterpret_cast<const int4*>(parents + s);

        float S = 0.f, D = 0.f;
        for (int i = tid; i < nq; i += BLOCK) {
            ushort4 yh = *reinterpret_cast<const ushort4*>(&row_bf[s + 4 * i]);
            int4    pa = pa4[i];
            float p0 = __expf(bf2f(yh.x) - m) * invZ;
            float p1 = __expf(bf2f(yh.y) - m) * invZ;
            float p2 = __expf(bf2f(yh.z) - m) * invZ;
            float p3 = __expf(bf2f(yh.w) - m) * invZ;
            float pp0 = __expf(bf2f(row_bf[pa.x]) - mp) * invZp;
            float pp1 = __expf(bf2f(row_bf[pa.y]) - mp) * invZp;
            float pp2 = __expf(bf2f(row_bf[pa.z]) - mp) * invZp;
            float pp3 = __expf(bf2f(row_bf[pa.w]) - mp) * invZp;
            S += (__expf(p0) + __expf(p1)) + (__expf(p2) + __expf(p3));
            D += fmaxf(p0 - pp0, 0.f) + fmaxf(p1 - pp1, 0.f)
               + fmaxf(p2 - pp2, 0.f) + fmaxf(p3 - pp3, 0.f);
        }
        S = waveSum(S); D = waveSum(D);
        if (lid == 0) {
            sc[wid * 8 + (l - 1)]     = S;
            sc[wid * 8 + 4 + (l - 1)] = D;
        }
    }
    __syncthreads();

    if (tid < 6) {
        int lm = tid % 3, isD = tid / 3;
        float a = 0.f;
        for (int w = 0; w < NW; ++w) a += sc[w * 8 + isD * 4 + lm];
        fin[tid] = a;
    }
    __syncthreads();

    if (tid == 0) {
        float loss = 0.f;
#pragma unroll
        for (int l = 1; l < H; ++l) {
            float S   = fin[l - 1];
            float D   = fin[3 + l - 1];
            float dot = dot_s[l] * invZ_s[l];
            loss += alpha[l] * (logf(S) * yts_s[l] - dot + D / (float)LSIZE[l]);
        }
        partial[b] = loss;
    }
}

__global__ __launch_bounds__(1024) void tax_reduce(
    const float* __restrict__ partial, float* __restrict__ out)
{
    __shared__ float red[16];
    const int tid = threadIdx.x, wid = tid >> 6, lid = tid & 63;
    float v = 0.f;
    for (int i = tid; i < BATCH; i += 1024) v += partial[i];
    v = waveSum(v);
    if (lid == 0) red[wid] = v;
    __syncthreads();
    if (wid == 0) {
        float x = (lid < 16) ? red[lid] : 0.f;
        x = waveSum(x);
        if (lid == 0) out[0] = x * (1.0f / (float)BATCH);
    }
}

extern "C" void kernel_launch(void* const* d_in, const int* in_sizes, int n_in,
                              void* d_out, int out_size, void* d_ws, size_t ws_size,
                              hipStream_t stream) {
    const float* y_pred  = (const float*)d_in[0];
    const float* y_true  = (const float*)d_in[1];
    const int*   parents = (const int*)d_in[2];
    const float* alpha   = (const float*)d_in[3];
    float* partial = (float*)d_ws;           // BATCH floats = 16 KB scratch
    float* out     = (float*)d_out;

    tax_main<<<dim3(BATCH), dim3(BLOCK), 0, stream>>>(y_pred, y_true, parents, alpha, partial);
    tax_reduce<<<dim3(1), dim3(1024), 0, stream>>>(partial, out);
}